// Round 7
// baseline (188.780 us; speedup 1.0000x reference)
//
#include <hip/hip_runtime.h>

#define N_EMB 16384
#define DIM 128
#define NSPLIT 8
#define CPS (N_EMB / NSPLIT) /* 2048 cols per split */
#define BN 128
#define NCT (CPS / BN) /* 16 column tiles per block */
#define NLAB 64

typedef __bf16 bf16x8 __attribute__((ext_vector_type(8)));
typedef float f32x4 __attribute__((ext_vector_type(4)));
typedef unsigned short us8 __attribute__((ext_vector_type(8)));
typedef unsigned int u32;

#define SCALE 2.8853900817779268f /* (1/T)*log2(e), T=0.5 */
#define LN2 0.6931471805599453f

__device__ inline float fast_exp2(float x) {
#if __has_builtin(__builtin_amdgcn_exp2f)
  return __builtin_amdgcn_exp2f(x);
#else
  return exp2f(x);
#endif
}
__device__ inline float fast_log2(float x) {
#if __has_builtin(__builtin_amdgcn_logf)
  return __builtin_amdgcn_logf(x);
#else
  return log2f(x);
#endif
}

// fp32 -> bf16 RNE (finite inputs)
__device__ inline unsigned short f2bf(float f) {
  unsigned int u = __float_as_uint(f);
  u += 0x7fffu + ((u >> 16) & 1u);
  return (unsigned short)(u >> 16);
}

// global->LDS DMA, 16 B per lane. LDS dest = wave-uniform base + lane*16.
__device__ inline void gll16(const unsigned short* g, unsigned short* l) {
  __builtin_amdgcn_global_load_lds(
      (const __attribute__((address_space(1))) u32*)g,
      (__attribute__((address_space(3))) u32*)l, 16, 0, 0);
}

// ---------------------------------------------------------------------------
// Counting sort by label, wave-parallel (verified rounds 3/4/6).
// ---------------------------------------------------------------------------
__global__ __launch_bounds__(1024) void perm_kernel(
    const int* __restrict__ labels, int* __restrict__ perm,
    int* __restrict__ gstart) {
  __shared__ int whist[16][NLAB];
  __shared__ int htot[NLAB];
  const int tid = threadIdx.x;
  const int w = tid >> 6, lane = tid & 63;
  whist[w][lane] = 0;
  __syncthreads();
  const int base_i = w * 1024;
  int mylab[16];
#pragma unroll
  for (int k = 0; k < 16; ++k) {
    int lab = labels[base_i + k * 64 + lane];
    mylab[k] = lab;
    atomicAdd(&whist[w][lab], 1);
  }
  __syncthreads();
  if (tid < NLAB) {
    int s = 0;
#pragma unroll
    for (int ww = 0; ww < 16; ++ww) {
      int t = whist[ww][tid];
      whist[ww][tid] = s;
      s += t;
    }
    htot[tid] = s;
  }
  __syncthreads();
  if (tid == 0) {
    int s = 0;
    for (int l = 0; l < NLAB; ++l) {
      int t = htot[l];
      gstart[l] = s;
      htot[l] = s;
      s += t;
    }
    gstart[NLAB] = s;
  }
  __syncthreads();
  whist[w][lane] += htot[lane];
  __syncthreads();
#pragma unroll
  for (int k = 0; k < 16; ++k) {
    int lab = mylab[k];
    int pos = atomicAdd(&whist[w][lab], 1);
    perm[pos] = base_i + k * 64 + lane;
  }
}

// ---------------------------------------------------------------------------
// Gather (permuted) + fp32->bf16 convert into fragment-linear layout.
// Fragment (T global 16-row tile, ks) lives at
// (T>>3)*16384 + ((T&7)*4+ks)*512 + lane*8 -- lane-contiguous 16B/lane.
// ---------------------------------------------------------------------------
__global__ __launch_bounds__(256) void preconv(
    const float* __restrict__ emb, const int* __restrict__ perm,
    unsigned short* __restrict__ eraw) {
  const int tid = threadIdx.x;
  const int tile = blockIdx.x >> 2;
  const int part = blockIdx.x & 3;
  const size_t base = (size_t)tile * (128 * DIM);
#pragma unroll
  for (int i = 0; i < 2; ++i) {
    int G = part * 512 + i * 256 + tid;
    int col16 = G & 15;
    int qd = (G >> 4) & 3;
    int ks = (G >> 6) & 3;
    int tc = G >> 8;
    int srow = perm[tile * 128 + tc * 16 + col16];
    const float* p = emb + (size_t)srow * DIM + ks * 32 + qd * 8;
    float4 a = *reinterpret_cast<const float4*>(p);
    float4 b = *reinterpret_cast<const float4*>(p + 4);
    us8 g;
    g[0] = f2bf(a.x); g[1] = f2bf(a.y); g[2] = f2bf(a.z); g[3] = f2bf(a.w);
    g[4] = f2bf(b.x); g[5] = f2bf(b.y); g[6] = f2bf(b.z); g[7] = f2bf(b.w);
    *reinterpret_cast<us8*>(eraw + base + (size_t)G * 8) = g;
  }
}

// Load one A fragment from raw bf16 and pre-scale by SCALE.
__device__ inline bf16x8 load_scaled(const unsigned short* p) {
  us8 v = *reinterpret_cast<const us8*>(p);
  us8 s;
#pragma unroll
  for (int j = 0; j < 8; ++j)
    s[j] = f2bf(__uint_as_float((u32)v[j] << 16) * SCALE);
  return *reinterpret_cast<bf16x8*>(&s);
}

// Load the 4 B fragments (K=128) of global 16-col tile T, raw (unscaled).
__device__ inline void loadB(bf16x8* dst,
                             const unsigned short* __restrict__ eraw, int T,
                             int lane) {
  const unsigned short* p =
      eraw + (size_t)(T >> 3) * (128 * DIM) + ((T & 7) * 4) * 512 + lane * 8;
#pragma unroll
  for (int ks = 0; ks < 4; ++ks)
    dst[ks] = *reinterpret_cast<const bf16x8*>(p + ks * 512);
}

// ---------------------------------------------------------------------------
// Fused main kernel. grid (128, NSPLIT+1), 128 threads (2 waves).
//  cs < NSPLIT : all-path -- EXACTLY the round-1 78 us core: BN=128 B tile
//    staged single-buffered via global_load_lds (bulk arrival), 2 barriers
//    per ct, each wave owns 64 rows with A in registers. This is the
//    empirically fastest GEMM core measured (r1=78 < r4 dbuf=91.8 <
//    r3 4-wave=94.5 < r6 no-LDS=117.8).
//  cs == NSPLIT: pos-path (block-diagonal positives + exact diag terms),
//    global->reg B stream (no barriers), l = x>>1, sub-chunk = x&1.
//    Dispatched last -> fills the all-path tail.
// ---------------------------------------------------------------------------
__global__ __launch_bounds__(128) void cl_fused(
    const unsigned short* __restrict__ eraw, const int* __restrict__ gstart,
    float* __restrict__ ws_all, float* __restrict__ ws_pos,
    float* __restrict__ ws_diag) {
  __shared__ unsigned short lds[BN * DIM]; // 32 KB B tile
  const int tid = threadIdx.x;
  const int lane = tid & 63;
  const int w = tid >> 6; // wave 0..1
  const int col16 = lane & 15;
  const int quad = lane >> 4;
  const int cs = blockIdx.y;

  if (cs < NSPLIT) {
    // ------------------------- all-path (r1 core) -------------------------
    const int r0 = blockIdx.x * 128;

    bf16x8 afrag[4][4];
#pragma unroll
    for (int tr = 0; tr < 4; ++tr) {
      const int T = (r0 >> 4) + w * 4 + tr;
      const unsigned short* p = eraw + (size_t)(T >> 3) * (128 * DIM) +
                                ((T & 7) * 4) * 512 + lane * 8;
#pragma unroll
      for (int ks = 0; ks < 4; ++ks) afrag[tr][ks] = load_scaled(p + ks * 512);
    }

    float all_p[16];
#pragma unroll
    for (int t = 0; t < 16; ++t) all_p[t] = 0.f;

    for (int ct = 0; ct < NCT; ++ct) {
      const int c0 = cs * CPS + ct * BN;
      __syncthreads(); // prior compute (or afrag preload) done before overwrite
      {
        const unsigned short* g = eraw + (size_t)(c0 >> 7) * (128 * DIM);
#pragma unroll
        for (int i = 0; i < 16; ++i) {
          int chunk = i * 2 + w;
          gll16(g + chunk * 512 + lane * 8, lds + chunk * 512);
        }
      }
      __syncthreads(); // vmcnt(0) drained -> B tile visible

#pragma unroll
      for (int tc = 0; tc < 8; ++tc) {
        bf16x8 bfr[4];
#pragma unroll
        for (int ks = 0; ks < 4; ++ks)
          bfr[ks] = *reinterpret_cast<const bf16x8*>(lds + (tc * 4 + ks) * 512 +
                                                     lane * 8);
#pragma unroll
        for (int tr = 0; tr < 4; ++tr) {
          f32x4 acc = {0.f, 0.f, 0.f, 0.f};
#pragma unroll
          for (int ks = 0; ks < 4; ++ks)
            acc = __builtin_amdgcn_mfma_f32_16x16x32_bf16(afrag[tr][ks],
                                                          bfr[ks], acc, 0, 0,
                                                          0);
          // C/D layout (verified): col = lane&15, row = quad*4 + r
#pragma unroll
          for (int r = 0; r < 4; ++r) all_p[tr * 4 + r] += fast_exp2(acc[r]);
        }
      }
    }

#pragma unroll
    for (int t = 0; t < 16; ++t) {
      float a = all_p[t];
#pragma unroll
      for (int m = 8; m >= 1; m >>= 1) a += __shfl_xor(a, m, 64);
      if (col16 == 0) {
        int row_g = r0 + w * 64 + (t >> 2) * 16 + quad * 4 + (t & 3);
        ws_all[cs * N_EMB + row_g] = a;
      }
    }
  } else {
    // ------------------------- pos-path -------------------------
    const int l = blockIdx.x >> 1;  // 0..63
    const int sub = blockIdx.x & 1; // 0..1
    const int gs = gstart[l], ge = gstart[l + 1];
    const int t0 = gs >> 4;        // first 16-row tile touching group
    const int t1 = (ge + 15) >> 4; // exclusive end

    for (int ta = t0 + sub * 2 + w; ta < t1; ta += 4) {
      bf16x8 af[4];
      const unsigned short* pa = eraw + (size_t)(ta >> 3) * (128 * DIM) +
                                 ((ta & 7) * 4) * 512 + lane * 8;
#pragma unroll
      for (int ks = 0; ks < 4; ++ks) af[ks] = load_scaled(pa + ks * 512);
      const int grow = ta * 16 + quad * 4; // this lane's 4 rows: grow+r
      float posr[4] = {0.f, 0.f, 0.f, 0.f};

      for (int tb = t0; tb < t1; ++tb) {
        bf16x8 bfr[4];
        loadB(bfr, eraw, tb, lane);
        f32x4 acc = {0.f, 0.f, 0.f, 0.f};
#pragma unroll
        for (int ks = 0; ks < 4; ++ks)
          acc = __builtin_amdgcn_mfma_f32_16x16x32_bf16(af[ks], bfr[ks], acc,
                                                        0, 0, 0);
        const int gcol = tb * 16 + col16;
        const bool colin = (gcol >= gs) && (gcol < ge);
#pragma unroll
        for (int r = 0; r < 4; ++r) {
          float e = fast_exp2(acc[r]);
          const int gr = grow + r;
          if (gcol == gr) {
            if (colin) ws_diag[gr] = e; // exactly one writer per row
          } else if (colin) {
            posr[r] += e;
          }
        }
      }

#pragma unroll
      for (int r = 0; r < 4; ++r) {
        float p = posr[r];
#pragma unroll
        for (int m = 8; m >= 1; m >>= 1) p += __shfl_xor(p, m, 64);
        const int gr = grow + r;
        if (col16 == 0 && gr >= gs && gr < ge) ws_pos[gr] = p;
      }
    }
  }
}

// ---------------------------------------------------------------------------
// Finalize: single block (saves a dispatch; ~10 us launch overhead each).
// ---------------------------------------------------------------------------
__global__ __launch_bounds__(1024) void fin(const float* __restrict__ ws_all,
                                            const float* __restrict__ ws_pos,
                                            const float* __restrict__ ws_diag,
                                            float* __restrict__ out) {
  __shared__ float s_t[1024];
  __shared__ int s_c[1024];
  const int tid = threadIdx.x;
  float tot = 0.f;
  int cnt = 0;
  for (int row = tid; row < N_EMB; row += 1024) {
    float a = 0.f;
#pragma unroll
    for (int s = 0; s < NSPLIT; ++s) a += ws_all[s * N_EMB + row];
    a -= ws_diag[row];
    const float p = ws_pos[row];
    if (p > 0.f) {
      tot += fast_log2(a) - fast_log2(p);
      cnt++;
    }
  }
  s_t[tid] = tot;
  s_c[tid] = cnt;
  __syncthreads();
  for (int s = 512; s > 0; s >>= 1) {
    if (tid < s) {
      s_t[tid] += s_t[tid + s];
      s_c[tid] += s_c[tid + s];
    }
    __syncthreads();
  }
  if (tid == 0)
    out[0] = (s_c[0] > 0) ? (s_t[0] * LN2 / (float)s_c[0]) : 0.f;
}

extern "C" void kernel_launch(void* const* d_in, const int* in_sizes, int n_in,
                              void* d_out, int out_size, void* d_ws,
                              size_t ws_size, hipStream_t stream) {
  const float* emb = (const float*)d_in[0];
  const int* labels = (const int*)d_in[1];

  unsigned short* eraw = (unsigned short*)d_ws;         // 4 MB bf16 frag-linear
  float* ws_all = (float*)(eraw + (size_t)N_EMB * DIM); // [NSPLIT][N] 512 KB
  float* ws_pos = ws_all + NSPLIT * N_EMB;              // [N] 64 KB
  float* ws_diag = ws_pos + N_EMB;                      // [N] 64 KB
  int* perm = (int*)(ws_diag + N_EMB);                  // [N] 64 KB
  int* gstart = perm + N_EMB;                           // [65]

  perm_kernel<<<1, 1024, 0, stream>>>(labels, perm, gstart);
  preconv<<<512, 256, 0, stream>>>(emb, perm, eraw);
  cl_fused<<<dim3(128, NSPLIT + 1), 128, 0, stream>>>(eraw, gstart, ws_all,
                                                      ws_pos, ws_diag);
  fin<<<1, 1024, 0, stream>>>(ws_all, ws_pos, ws_diag, (float*)d_out);
}

// Round 8
// 184.885 us; speedup vs baseline: 1.0211x; 1.0211x over previous
//
#include <hip/hip_runtime.h>

#define N_EMB 16384
#define DIM 128
#define NSPLIT 16
#define CPS (N_EMB / NSPLIT) /* 1024 cols per split */
#define BN 128
#define NCT (CPS / BN) /* 8 column tiles per block */
#define NLAB 64
#define POSY 4 /* pos-path slices, dispatched FIRST (y=0..3) */

typedef __bf16 bf16x8 __attribute__((ext_vector_type(8)));
typedef float f32x4 __attribute__((ext_vector_type(4)));
typedef unsigned short us8 __attribute__((ext_vector_type(8)));
typedef unsigned int u32;

#define SCALE 2.8853900817779268f /* (1/T)*log2(e), T=0.5 */
#define LN2 0.6931471805599453f

__device__ inline float fast_exp2(float x) {
#if __has_builtin(__builtin_amdgcn_exp2f)
  return __builtin_amdgcn_exp2f(x);
#else
  return exp2f(x);
#endif
}
__device__ inline float fast_log2(float x) {
#if __has_builtin(__builtin_amdgcn_logf)
  return __builtin_amdgcn_logf(x);
#else
  return log2f(x);
#endif
}

// fp32 -> bf16 RNE (finite inputs)
__device__ inline unsigned short f2bf(float f) {
  unsigned int u = __float_as_uint(f);
  u += 0x7fffu + ((u >> 16) & 1u);
  return (unsigned short)(u >> 16);
}

// global->LDS DMA, 16 B per lane. LDS dest = wave-uniform base + lane*16.
__device__ inline void gll16(const unsigned short* g, unsigned short* l) {
  __builtin_amdgcn_global_load_lds(
      (const __attribute__((address_space(1))) u32*)g,
      (__attribute__((address_space(3))) u32*)l, 16, 0, 0);
}

// ---------------------------------------------------------------------------
// prep: blocks 0..511 convert fp32 -> bf16 into fragment-linear layout in
// NATURAL row order (no permutation; all_sum is order-invariant). Block 512
// runs the counting sort by label (rows grouped for the pos path only).
// Fragment (T 16-row tile, ks) lives at
// (T>>3)*16384 + ((T&7)*4+ks)*512 + lane*8 -- lane-contiguous 16B/lane,
// where lane = quad*16+col16 holds row T*16+col16, dims ks*32+quad*8..+7.
// ---------------------------------------------------------------------------
__global__ __launch_bounds__(256) void prep(
    const float* __restrict__ emb, const int* __restrict__ labels,
    unsigned short* __restrict__ eraw, int* __restrict__ perm,
    int* __restrict__ gstart) {
  if (blockIdx.x < 512) {
    const int tid = threadIdx.x;
    const int tile = blockIdx.x >> 2;
    const int part = blockIdx.x & 3;
    const size_t base = (size_t)tile * (128 * DIM);
#pragma unroll
    for (int i = 0; i < 2; ++i) {
      int G = part * 512 + i * 256 + tid;
      int col16 = G & 15;
      int qd = (G >> 4) & 3;
      int ks = (G >> 6) & 3;
      int tc = G >> 8;
      int srow = tile * 128 + tc * 16 + col16;
      const float* p = emb + (size_t)srow * DIM + ks * 32 + qd * 8;
      float4 a = *reinterpret_cast<const float4*>(p);
      float4 b = *reinterpret_cast<const float4*>(p + 4);
      us8 g;
      g[0] = f2bf(a.x); g[1] = f2bf(a.y); g[2] = f2bf(a.z); g[3] = f2bf(a.w);
      g[4] = f2bf(b.x); g[5] = f2bf(b.y); g[6] = f2bf(b.z); g[7] = f2bf(b.w);
      *reinterpret_cast<us8*>(eraw + base + (size_t)G * 8) = g;
    }
  } else {
    // counting sort, 4 waves; per-wave histograms -> scan -> placement
    __shared__ int whist[4][NLAB];
    __shared__ int htot[NLAB];
    const int tid = threadIdx.x;
    const int w = tid >> 6, lane = tid & 63;
    whist[w][lane] = 0;
    __syncthreads();
    const int base_i = w * 4096;
    for (int k = 0; k < 64; ++k)
      atomicAdd(&whist[w][labels[base_i + k * 64 + lane]], 1);
    __syncthreads();
    if (tid < NLAB) {
      int s = 0;
#pragma unroll
      for (int ww = 0; ww < 4; ++ww) {
        int t = whist[ww][tid];
        whist[ww][tid] = s;
        s += t;
      }
      htot[tid] = s;
    }
    __syncthreads();
    if (tid == 0) {
      int s = 0;
      for (int l = 0; l < NLAB; ++l) {
        int t = htot[l];
        gstart[l] = s;
        htot[l] = s;
        s += t;
      }
      gstart[NLAB] = s;
    }
    __syncthreads();
    whist[w][lane] += htot[lane]; // absolute base per (wave,label)
    __syncthreads();
    for (int k = 0; k < 64; ++k) {
      int row = base_i + k * 64 + lane;
      int pos = atomicAdd(&whist[w][labels[row]], 1);
      perm[pos] = row;
    }
  }
}

// Load one A fragment from raw bf16 and pre-scale by SCALE.
__device__ inline bf16x8 load_scaled(const unsigned short* p) {
  us8 v = *reinterpret_cast<const us8*>(p);
  us8 s;
#pragma unroll
  for (int j = 0; j < 8; ++j)
    s[j] = f2bf(__uint_as_float((u32)v[j] << 16) * SCALE);
  return *reinterpret_cast<bf16x8*>(&s);
}

// Pointer to the 16B fragment chunk of physical row r, k-block ks, for a lane
// with given quad (lane>>4): dims ks*32+quad*8 .. +7.
__device__ inline const unsigned short* frag_ptr(
    const unsigned short* __restrict__ eraw, int r, int quad, int ks) {
  return eraw + (size_t)(r >> 7) * (128 * DIM) +
         (size_t)((((r >> 4) & 7) * 4 + ks) * 512 + (quad * 16 + (r & 15)) * 8);
}

// ---------------------------------------------------------------------------
// Fused main kernel. grid (128, POSY+NSPLIT), 128 threads (2 waves).
//  y < POSY   : pos-path, dispatched FIRST so the latency-bound pos blocks
//    overlap the all-path instead of trailing it (round-7 post-mortem: pos
//    as last slice with 2 chunks/label added a ~35 us serial tail).
//    512 short blocks: label = x>>1, chunk = y*2+(x&1) in 0..7; each wave
//    handles group row-tiles ti = chunk*2+w stride 16. Rows gathered
//    through perm[] (frag-linear eraw is in natural order).
//  y >= POSY  : all-path -- the round-1 78 us core untouched: BN=128 B tile
//    single-buffered via global_load_lds, 2 barriers per ct, 2-wave blocks,
//    each wave owns 64 rows with A in registers. NSPLIT=16 -> 2048 blocks
//    for ~5 resident blocks/CU of drain overlap.
// ---------------------------------------------------------------------------
__global__ __launch_bounds__(128) void cl_fused(
    const unsigned short* __restrict__ eraw, const int* __restrict__ perm,
    const int* __restrict__ gstart, float* __restrict__ ws_all,
    float* __restrict__ ws_pos, float* __restrict__ ws_diag) {
  __shared__ unsigned short lds[BN * DIM]; // 32 KB B tile (all-path only)
  const int tid = threadIdx.x;
  const int lane = tid & 63;
  const int w = tid >> 6; // wave 0..1
  const int col16 = lane & 15;
  const int quad = lane >> 4;

  if (blockIdx.y >= POSY) {
    // ------------------------- all-path (r1 core) -------------------------
    const int cs = blockIdx.y - POSY;
    const int r0 = blockIdx.x * 128;

    bf16x8 afrag[4][4];
#pragma unroll
    for (int tr = 0; tr < 4; ++tr) {
      const int T = (r0 >> 4) + w * 4 + tr;
      const unsigned short* p = eraw + (size_t)(T >> 3) * (128 * DIM) +
                                ((T & 7) * 4) * 512 + lane * 8;
#pragma unroll
      for (int ks = 0; ks < 4; ++ks) afrag[tr][ks] = load_scaled(p + ks * 512);
    }

    float all_p[16];
#pragma unroll
    for (int t = 0; t < 16; ++t) all_p[t] = 0.f;

    for (int ct = 0; ct < NCT; ++ct) {
      __syncthreads(); // prior compute (or afrag preload) done before overwrite
      {
        const unsigned short* g =
            eraw + (size_t)(cs * NCT + ct) * (128 * DIM);
#pragma unroll
        for (int i = 0; i < 16; ++i) {
          int chunk = i * 2 + w;
          gll16(g + chunk * 512 + lane * 8, lds + chunk * 512);
        }
      }
      __syncthreads(); // vmcnt(0) drained -> B tile visible

#pragma unroll
      for (int tc = 0; tc < 8; ++tc) {
        bf16x8 bfr[4];
#pragma unroll
        for (int ks = 0; ks < 4; ++ks)
          bfr[ks] = *reinterpret_cast<const bf16x8*>(lds + (tc * 4 + ks) * 512 +
                                                     lane * 8);
#pragma unroll
        for (int tr = 0; tr < 4; ++tr) {
          f32x4 acc = {0.f, 0.f, 0.f, 0.f};
#pragma unroll
          for (int ks = 0; ks < 4; ++ks)
            acc = __builtin_amdgcn_mfma_f32_16x16x32_bf16(afrag[tr][ks],
                                                          bfr[ks], acc, 0, 0,
                                                          0);
          // C/D layout (verified): col = lane&15, row = quad*4 + r
#pragma unroll
          for (int r = 0; r < 4; ++r) all_p[tr * 4 + r] += fast_exp2(acc[r]);
        }
      }
    }

#pragma unroll
    for (int t = 0; t < 16; ++t) {
      float a = all_p[t];
#pragma unroll
      for (int m = 8; m >= 1; m >>= 1) a += __shfl_xor(a, m, 64);
      if (col16 == 0) {
        int row_g = r0 + w * 64 + (t >> 2) * 16 + quad * 4 + (t & 3);
        ws_all[(size_t)row_g * NSPLIT + cs] = a; // [row][split] for fin
      }
    }
  } else {
    // ------------------------- pos-path (gathered) -------------------------
    const int l = blockIdx.x >> 1;                    // 0..63
    const int chunk = blockIdx.y * 2 + (blockIdx.x & 1); // 0..7
    const int gs = gstart[l], ge = gstart[l + 1];
    const int rows = ge - gs;
    const int nt = (rows + 15) >> 4; // 16-row tiles in group

    for (int ti = chunk * 2 + w; ti < nt; ti += 16) {
      // gathered A fragments: lane's group row = ti*16+col16
      const int ga = gs + ti * 16 + col16;
      const int ra = (ga < ge) ? perm[ga] : perm[gs]; // dummy if past end
      bf16x8 af[4];
#pragma unroll
      for (int ks = 0; ks < 4; ++ks)
        af[ks] = load_scaled(frag_ptr(eraw, ra, quad, ks));
      const int grow_l = ti * 16 + quad * 4; // group-local rows grow_l+r
      float posr[4] = {0.f, 0.f, 0.f, 0.f};

      for (int tj = 0; tj < nt; ++tj) {
        const int gb = gs + tj * 16 + col16;
        const int rb = (gb < ge) ? perm[gb] : perm[gs];
        bf16x8 bfr[4];
#pragma unroll
        for (int ks = 0; ks < 4; ++ks)
          bfr[ks] = *reinterpret_cast<const bf16x8*>(
              frag_ptr(eraw, rb, quad, ks));
        f32x4 acc = {0.f, 0.f, 0.f, 0.f};
#pragma unroll
        for (int ks = 0; ks < 4; ++ks)
          acc = __builtin_amdgcn_mfma_f32_16x16x32_bf16(af[ks], bfr[ks], acc,
                                                        0, 0, 0);
        const int gcol_l = tj * 16 + col16;
        const bool colin = gcol_l < rows;
#pragma unroll
        for (int r = 0; r < 4; ++r) {
          float e = fast_exp2(acc[r]);
          const int i_l = grow_l + r;
          if (gcol_l == i_l) {
            if (colin) ws_diag[perm[gs + i_l]] = e; // one writer per row
          } else if (colin) {
            posr[r] += e;
          }
        }
      }

#pragma unroll
      for (int r = 0; r < 4; ++r) {
        float p = posr[r];
#pragma unroll
        for (int m = 8; m >= 1; m >>= 1) p += __shfl_xor(p, m, 64);
        const int i_l = grow_l + r;
        if (col16 == 0 && i_l < rows) ws_pos[perm[gs + i_l]] = p;
      }
    }
  }
}

// ---------------------------------------------------------------------------
// Finalize: 16-block partial reduce (coalesced [row][split] reads), then one
// wave combines. all = sum(splits) - diag (bitwise-matching term).
// ---------------------------------------------------------------------------
__global__ __launch_bounds__(1024) void fin1(
    const float* __restrict__ ws_all, const float* __restrict__ ws_pos,
    const float* __restrict__ ws_diag, float* __restrict__ part_tot,
    int* __restrict__ part_cnt) {
  __shared__ float s_t[1024];
  __shared__ int s_c[1024];
  const int tid = threadIdx.x;
  const int row = blockIdx.x * 1024 + tid;
  const float4* pa = reinterpret_cast<const float4*>(ws_all + (size_t)row * NSPLIT);
  float a = 0.f;
#pragma unroll
  for (int q = 0; q < NSPLIT / 4; ++q) {
    float4 v = pa[q];
    a += v.x + v.y + v.z + v.w;
  }
  a -= ws_diag[row];
  const float p = ws_pos[row];
  float t = 0.f;
  int c = 0;
  if (p > 0.f) {
    t = fast_log2(a) - fast_log2(p);
    c = 1;
  }
  s_t[tid] = t;
  s_c[tid] = c;
  __syncthreads();
  for (int s = 512; s > 0; s >>= 1) {
    if (tid < s) {
      s_t[tid] += s_t[tid + s];
      s_c[tid] += s_c[tid + s];
    }
    __syncthreads();
  }
  if (tid == 0) {
    part_tot[blockIdx.x] = s_t[0];
    part_cnt[blockIdx.x] = s_c[0];
  }
}

__global__ __launch_bounds__(64) void fin2(const float* __restrict__ part_tot,
                                           const int* __restrict__ part_cnt,
                                           float* __restrict__ out) {
  const int tid = threadIdx.x;
  float t = (tid < 16) ? part_tot[tid] : 0.f;
  int c = (tid < 16) ? part_cnt[tid] : 0;
#pragma unroll
  for (int m = 8; m >= 1; m >>= 1) {
    t += __shfl_xor(t, m, 64);
    c += __shfl_xor(c, m, 64);
  }
  if (tid == 0) out[0] = (c > 0) ? (t * LN2 / (float)c) : 0.f;
}

extern "C" void kernel_launch(void* const* d_in, const int* in_sizes, int n_in,
                              void* d_out, int out_size, void* d_ws,
                              size_t ws_size, hipStream_t stream) {
  const float* emb = (const float*)d_in[0];
  const int* labels = (const int*)d_in[1];

  unsigned short* eraw = (unsigned short*)d_ws;         // 4 MB bf16 frag-linear
  float* ws_all = (float*)(eraw + (size_t)N_EMB * DIM); // [N][NSPLIT] 1 MB
  float* ws_pos = ws_all + (size_t)N_EMB * NSPLIT;      // [N] 64 KB
  float* ws_diag = ws_pos + N_EMB;                      // [N] 64 KB
  float* part_tot = ws_diag + N_EMB;                    // [16]
  int* part_cnt = (int*)(part_tot + 16);                // [16]
  int* perm = part_cnt + 16;                            // [N] 64 KB
  int* gstart = perm + N_EMB;                           // [65]

  prep<<<513, 256, 0, stream>>>(emb, labels, eraw, perm, gstart);
  cl_fused<<<dim3(128, POSY + NSPLIT), 128, 0, stream>>>(eraw, perm, gstart,
                                                         ws_all, ws_pos,
                                                         ws_diag);
  fin1<<<16, 1024, 0, stream>>>(ws_all, ws_pos, ws_diag, part_tot, part_cnt);
  fin2<<<1, 64, 0, stream>>>(part_tot, part_cnt, (float*)d_out);
}

// Round 10
// 173.841 us; speedup vs baseline: 1.0859x; 1.0635x over previous
//
#include <hip/hip_runtime.h>

#define N_EMB 16384
#define DIM 128
#define NSPLIT 8
#define CPS (N_EMB / NSPLIT) /* 2048 cols per split */
#define BN 128
#define NCT (CPS / BN) /* 16 column tiles per block */

typedef __bf16 bf16x8 __attribute__((ext_vector_type(8)));
typedef float f32x4 __attribute__((ext_vector_type(4)));
typedef unsigned short us8 __attribute__((ext_vector_type(8)));
typedef unsigned int u32;

#define SCALE 2.8853900817779268f /* (1/T)*log2(e), T=0.5 */
#define LN2 0.6931471805599453f

__device__ inline float fast_exp2(float x) {
#if __has_builtin(__builtin_amdgcn_exp2f)
  return __builtin_amdgcn_exp2f(x);
#else
  return exp2f(x);
#endif
}
__device__ inline float fast_log2(float x) {
#if __has_builtin(__builtin_amdgcn_logf)
  return __builtin_amdgcn_logf(x);
#else
  return log2f(x);
#endif
}

// fp32 -> bf16 RNE (finite inputs)
__device__ inline unsigned short f2bf(float f) {
  unsigned int u = __float_as_uint(f);
  u += 0x7fffu + ((u >> 16) & 1u);
  return (unsigned short)(u >> 16);
}

// global->LDS DMA, 16 B per lane. LDS dest = wave-uniform base + lane*16.
__device__ inline void gll16(const unsigned short* g, unsigned short* l) {
  __builtin_amdgcn_global_load_lds(
      (const __attribute__((address_space(1))) u32*)g,
      (__attribute__((address_space(3))) u32*)l, 16, 0, 0);
}

// ---------------------------------------------------------------------------
// fp32 -> bf16 convert into fragment-linear layout, NATURAL row order
// (no permutation anywhere this round). Fragment (T 16-row tile, ks) lives at
// (T>>3)*16384 + ((T&7)*4+ks)*512 + lane*8; lane = quad*16+col16 holds row
// T*16+col16, dims ks*32+quad*8..+7. Reads are fully coalesced float4 pairs.
// ---------------------------------------------------------------------------
__global__ __launch_bounds__(256) void preconv(
    const float* __restrict__ emb, unsigned short* __restrict__ eraw) {
  const int tid = threadIdx.x;
  const int tile = blockIdx.x >> 2;
  const int part = blockIdx.x & 3;
  const size_t base = (size_t)tile * (128 * DIM);
#pragma unroll
  for (int i = 0; i < 2; ++i) {
    int G = part * 512 + i * 256 + tid;
    int col16 = G & 15;
    int qd = (G >> 4) & 3;
    int ks = (G >> 6) & 3;
    int tc = G >> 8;
    int srow = tile * 128 + tc * 16 + col16;
    const float* p = emb + (size_t)srow * DIM + ks * 32 + qd * 8;
    float4 a = *reinterpret_cast<const float4*>(p);
    float4 b = *reinterpret_cast<const float4*>(p + 4);
    us8 g;
    g[0] = f2bf(a.x); g[1] = f2bf(a.y); g[2] = f2bf(a.z); g[3] = f2bf(a.w);
    g[4] = f2bf(b.x); g[5] = f2bf(b.y); g[6] = f2bf(b.z); g[7] = f2bf(b.w);
    *reinterpret_cast<us8*>(eraw + base + (size_t)G * 8) = g;
  }
}

// Load one A fragment from raw bf16 and pre-scale by SCALE.
__device__ inline bf16x8 load_scaled(const unsigned short* p) {
  us8 v = *reinterpret_cast<const us8*>(p);
  us8 s;
#pragma unroll
  for (int j = 0; j < 8; ++j)
    s[j] = f2bf(__uint_as_float((u32)v[j] << 16) * SCALE);
  return *reinterpret_cast<bf16x8*>(&s);
}

// ---------------------------------------------------------------------------
// Main kernel: the round-1 measured-78us GEMM core (BN=128 single-buffer LDS
// B tile via global_load_lds, 2 barriers/ct, 2-wave blocks, 64 rows/wave,
// A scaled in registers) + round-0's verified masked epilogue computing BOTH
// all_sum and pos_sum in one pass (label compare + cndmask; diag zeroed
// in-kernel). No sort, no perm, no separate pos kernel, no pos tail.
// Grid (128, NSPLIT=8) = 1024 blocks. Outputs [row][split] for coalesced fin.
// ---------------------------------------------------------------------------
__global__ __launch_bounds__(128) void cl_main(
    const unsigned short* __restrict__ eraw, const int* __restrict__ labels,
    float* __restrict__ ws_all, float* __restrict__ ws_pos) {
  __shared__ unsigned short lds[BN * DIM]; // 32 KB B tile
  const int tid = threadIdx.x;
  const int lane = tid & 63;
  const int w = tid >> 6; // wave 0..1, owns rows [r0+w*64, r0+w*64+64)
  const int col16 = lane & 15;
  const int quad = lane >> 4;
  const int r0 = blockIdx.x * 128;
  const int cs = blockIdx.y;

  // A-frag: lane holds A[m=lane&15][k=quad*8+j] for 16-row tile T, scaled.
  bf16x8 afrag[4][4];
#pragma unroll
  for (int tr = 0; tr < 4; ++tr) {
    const int T = (r0 >> 4) + w * 4 + tr;
    const unsigned short* p = eraw + (size_t)(T >> 3) * (128 * DIM) +
                              ((T & 7) * 4) * 512 + lane * 8;
#pragma unroll
    for (int ks = 0; ks < 4; ++ks) afrag[tr][ks] = load_scaled(p + ks * 512);
  }

  int labi[16];
  float all_p[16], pos_p[16];
#pragma unroll
  for (int t = 0; t < 16; ++t) {
    labi[t] = labels[r0 + w * 64 + (t >> 2) * 16 + quad * 4 + (t & 3)];
    all_p[t] = 0.f;
    pos_p[t] = 0.f;
  }

  for (int ct = 0; ct < NCT; ++ct) {
    const int c0 = cs * CPS + ct * BN;
    __syncthreads(); // prior compute (or afrag preload) done before overwrite
    {
      const unsigned short* g = eraw + (size_t)(c0 >> 7) * (128 * DIM);
#pragma unroll
      for (int i = 0; i < 16; ++i) {
        int chunk = i * 2 + w;
        gll16(g + chunk * 512 + lane * 8, lds + chunk * 512);
      }
    }
    __syncthreads(); // vmcnt(0) drained -> B tile visible

#pragma unroll
    for (int tc = 0; tc < 8; ++tc) {
      bf16x8 bfr[4];
#pragma unroll
      for (int ks = 0; ks < 4; ++ks)
        bfr[ks] = *reinterpret_cast<const bf16x8*>(lds + (tc * 4 + ks) * 512 +
                                                   lane * 8);
      const int labj = labels[c0 + tc * 16 + col16];
#pragma unroll
      for (int tr = 0; tr < 4; ++tr) {
        f32x4 acc = {0.f, 0.f, 0.f, 0.f};
#pragma unroll
        for (int ks = 0; ks < 4; ++ks)
          acc = __builtin_amdgcn_mfma_f32_16x16x32_bf16(afrag[tr][ks], bfr[ks],
                                                        acc, 0, 0, 0);
        // C/D layout (verified): col = lane&15, row = quad*4 + r
        const bool diag = (c0 + tc * 16) == (r0 + w * 64 + tr * 16);
#pragma unroll
        for (int r = 0; r < 4; ++r) {
          float e = fast_exp2(acc[r]);
          if (diag && (quad * 4 + r) == col16) e = 0.f; // exclude j == i
          all_p[tr * 4 + r] += e;
          pos_p[tr * 4 + r] += (labi[tr * 4 + r] == labj) ? e : 0.f;
        }
      }
    }
  }

  // Reduce across the 16 col-lanes sharing each row; store [row][split].
#pragma unroll
  for (int t = 0; t < 16; ++t) {
    float a = all_p[t], p = pos_p[t];
#pragma unroll
    for (int m = 8; m >= 1; m >>= 1) {
      a += __shfl_xor(a, m, 64);
      p += __shfl_xor(p, m, 64);
    }
    if (col16 == 0) {
      int row_g = r0 + w * 64 + (t >> 2) * 16 + quad * 4 + (t & 3);
      ws_all[(size_t)row_g * NSPLIT + cs] = a;
      ws_pos[(size_t)row_g * NSPLIT + cs] = p;
    }
  }
}

// ---------------------------------------------------------------------------
// Finalize: single block, 1024 threads (r0-proven shape); [row][split]
// layout gives float4-coalesced reads.
// ---------------------------------------------------------------------------
__global__ __launch_bounds__(1024) void fin(const float* __restrict__ ws_all,
                                            const float* __restrict__ ws_pos,
                                            float* __restrict__ out) {
  __shared__ float s_t[1024];
  __shared__ int s_c[1024];
  const int tid = threadIdx.x;
  float tot = 0.f;
  int cnt = 0;
  for (int row = tid; row < N_EMB; row += 1024) {
    const float4* pa = reinterpret_cast<const float4*>(ws_all + (size_t)row * NSPLIT);
    const float4* pp = reinterpret_cast<const float4*>(ws_pos + (size_t)row * NSPLIT);
    float a = 0.f, p = 0.f;
#pragma unroll
    for (int q = 0; q < NSPLIT / 4; ++q) {
      float4 va = pa[q];
      float4 vp = pp[q];
      a += va.x + va.y + va.z + va.w;
      p += vp.x + vp.y + vp.z + vp.w;
    }
    if (p > 0.f) {
      tot += fast_log2(a) - fast_log2(p);
      cnt++;
    }
  }
  s_t[tid] = tot;
  s_c[tid] = cnt;
  __syncthreads();
  for (int s = 512; s > 0; s >>= 1) {
    if (tid < s) {
      s_t[tid] += s_t[tid + s];
      s_c[tid] += s_c[tid + s];
    }
    __syncthreads();
  }
  if (tid == 0)
    out[0] = (s_c[0] > 0) ? (s_t[0] * LN2 / (float)s_c[0]) : 0.f;
}

extern "C" void kernel_launch(void* const* d_in, const int* in_sizes, int n_in,
                              void* d_out, int out_size, void* d_ws,
                              size_t ws_size, hipStream_t stream) {
  const float* emb = (const float*)d_in[0];
  const int* labels = (const int*)d_in[1];

  unsigned short* eraw = (unsigned short*)d_ws;         // 4 MB bf16 frag-linear
  float* ws_all = (float*)(eraw + (size_t)N_EMB * DIM); // [N][NSPLIT] 512 KB
  float* ws_pos = ws_all + (size_t)N_EMB * NSPLIT;      // [N][NSPLIT] 512 KB

  preconv<<<512, 256, 0, stream>>>(emb, eraw);
  cl_main<<<dim3(128, NSPLIT), 128, 0, stream>>>(eraw, labels, ws_all, ws_pos);
  fin<<<1, 1024, 0, stream>>>(ws_all, ws_pos, (float*)d_out);
}